// Round 3
// baseline (159.354 us; speedup 1.0000x reference)
//
#include <hip/hip_runtime.h>
#include <math.h>

#define Tt 4096
#define KCH 16

// 0.5 * log2(e): folds the 1/sqrt(d)=0.5 softmax scale AND the base-e->base-2
// conversion into q (and the bias table), so the inner loop uses raw v_exp_f32.
#define QSCALE 0.72134752044448170f

typedef unsigned long long u64;
typedef float v2f __attribute__((ext_vector_type(2)));

// Packed fp32 FMA: d = a2 * k2 + c (both halves). k2 is a wave-uniform SGPR
// pair (the only scalar operand); a2/c are VGPR pairs.
__device__ __forceinline__ v2f pkfma(v2f a2, u64 k2, v2f c) {
  v2f d;
  asm("v_pk_fma_f32 %0, %1, %2, %3" : "=v"(d) : "v"(a2), "s"(k2), "v"(c));
  return d;
}

__device__ __forceinline__ float gelu_tanh(float x) {
  // 0.7978845608 * 2 * log2(e) = 2.3022081159 ; e^{2u} computed as exp2.
  float x3 = x * x * x;
  float u2 = 2.3022081159f * (x + 0.044715f * x3);
  float e = __builtin_amdgcn_exp2f(u2);
  float th = 1.0f - 2.0f * __builtin_amdgcn_rcpf(e + 1.0f);
  return 0.5f * x * (1.0f + th);
}

// Kernel 1: x1 = circ_conv3x3(gelu(x)) + x ; then q,k,v projections from y=x1/sqrt(2).
// q is pre-scaled by 0.5*log2(e). Also writes the pair-interleaved K layout
// kpk: for key pair (2p,2p+1), u64 component c = (lo=k_{2p+1}[c], hi=k_{2p}[c]).
__global__ __launch_bounds__(64) void k_pre(
    const float* __restrict__ x, const float* __restrict__ cW,
    const float* __restrict__ cb, const float* __restrict__ Wq,
    const float* __restrict__ Wk, const float* __restrict__ Wv,
    float* __restrict__ x1, float* __restrict__ qo,
    float* __restrict__ ko, float* __restrict__ vo,
    float* __restrict__ kpk) {
  const int bi = blockIdx.x;          // b*64 + i
  const int b = bi >> 6, i = bi & 63;
  const int j = threadIdx.x;          // 0..63
  float acc[8];
#pragma unroll
  for (int c = 0; c < 8; c++) acc[c] = cb[c];
#pragma unroll
  for (int di = 0; di < 3; di++) {
    const int ii = (i + di + 63) & 63;
#pragma unroll
    for (int dj = 0; dj < 3; dj++) {
      const int jj = (j + dj + 63) & 63;
      const float4* px = (const float4*)(x + ((b * 64 + ii) * 64 + jj) * 8);
      float4 a0 = px[0], a1 = px[1];
      float g[8];
      g[0] = gelu_tanh(a0.x); g[1] = gelu_tanh(a0.y);
      g[2] = gelu_tanh(a0.z); g[3] = gelu_tanh(a0.w);
      g[4] = gelu_tanh(a1.x); g[5] = gelu_tanh(a1.y);
      g[6] = gelu_tanh(a1.z); g[7] = gelu_tanh(a1.w);
      const float* w = cW + (di * 3 + dj) * 64;
#pragma unroll
      for (int ci = 0; ci < 8; ci++) {
        const float gv = g[ci];
#pragma unroll
        for (int c = 0; c < 8; c++) acc[c] += gv * w[ci * 8 + c];
      }
    }
  }
  const int t = i * 64 + j;
  const float4* pxc = (const float4*)(x + (b * Tt + t) * 8);
  float4 c0 = pxc[0], c1 = pxc[1];
  float xv[8];
  xv[0] = acc[0] + c0.x; xv[1] = acc[1] + c0.y;
  xv[2] = acc[2] + c0.z; xv[3] = acc[3] + c0.w;
  xv[4] = acc[4] + c1.x; xv[5] = acc[5] + c1.y;
  xv[6] = acc[6] + c1.z; xv[7] = acc[7] + c1.w;
  float4* px1 = (float4*)(x1 + (b * Tt + t) * 8);
  px1[0] = make_float4(xv[0], xv[1], xv[2], xv[3]);
  px1[1] = make_float4(xv[4], xv[5], xv[6], xv[7]);
  float y[8];
#pragma unroll
  for (int c = 0; c < 8; c++) y[c] = xv[c] * 0.7071067811865475f;
#pragma unroll
  for (int h = 0; h < 2; h++) {
    float qe[4], ke[4], ve[4];
#pragma unroll
    for (int d = 0; d < 4; d++) {
      const int e = h * 4 + d;
      float sq = 0.f, sk = 0.f, sv = 0.f;
#pragma unroll
      for (int c = 0; c < 8; c++) {
        sq += y[c] * Wq[c * 8 + e];
        sk += y[c] * Wk[c * 8 + e];
        sv += y[c] * Wv[c * 8 + e];
      }
      qe[d] = sq * QSCALE;  // fold softmax scale + log2(e) into q
      ke[d] = sk; ve[d] = sv;
    }
    const int idx = (b * 2 + h) * Tt + t;
    ((float4*)qo)[idx] = make_float4(qe[0], qe[1], qe[2], qe[3]);
    ((float4*)ko)[idx] = make_float4(ke[0], ke[1], ke[2], ke[3]);
    ((float4*)vo)[idx] = make_float4(ve[0], ve[1], ve[2], ve[3]);
    // pair-interleaved K for k_attn: word (pair*8 + c*2 + slot); odd key -> lo
    float* kp2 = kpk + (((size_t)(b * 2 + h) * 2048 + (t >> 1)) << 3) + ((t & 1) ? 0 : 1);
    kp2[0] = ke[0]; kp2[2] = ke[1]; kp2[4] = ke[2]; kp2[6] = ke[3];
  }
}

// Kernel 2: split-K softmax denominator. Z_t = sum_j exp2(q_t.k_j + c*P[t,j]).
// Keys processed in pairs via v_pk_fma_f32: K comes from the pair-interleaved
// kpk layout as wave-uniform SGPR pairs (s_load_dwordx8 per key pair), the two
// biases are adjacent in the doubled LDS table (one ds_read2_b32, lo = odd key,
// matching the kpk interleave). Same fma nesting as scalar version -> bit-identical.
__global__ __launch_bounds__(64) void k_attn(
    const float* __restrict__ qo, const float* __restrict__ kpk,
    const float* __restrict__ pos, float* __restrict__ part) {
  const int id = blockIdx.x;
  const int qblk = id & 63;
  const int bh = (id >> 6) & 3;
  const int chunk = id >> 8;
  const int h = bh & 1;
  const int lane = threadIdx.x;
  __shared__ float posr[4][128];
#pragma unroll
  for (int r = 0; r < 4; r++) {
    const int j1 = chunk * 4 + r;
    const int row = (qblk - j1) & 63;   // i1 = qblk (query row, wave-uniform)
    const float v = QSCALE * pos[(h * 64 + row) * 64 + lane];
    posr[r][lane] = v;
    posr[r][lane + 64] = v;             // period-64 duplicate
  }
  __syncthreads();
  const int t1 = qblk * 64 + lane;
  const float4 qv = ((const float4*)qo)[bh * Tt + t1];
  const v2f qx2 = {qv.x, qv.x}, qy2 = {qv.y, qv.y};
  const v2f qz2 = {qv.z, qv.z}, qw2 = {qv.w, qv.w};
  float Z0 = 0.0f, Z1 = 0.0f;
#pragma unroll
  for (int r = 0; r < 4; r++) {
    const float* prow = &posr[r][lane + 1];
    const u64* kq = (const u64*)kpk + ((size_t)(bh * 2048 + chunk * 128 + r * 32) << 2);
#pragma unroll 8
    for (int jp = 0; jp < 32; jp++) {
      // bias pair: (lo, hi) = (posr[lane+62-2jp], posr[lane+63-2jp])
      //          = (bias of key 2jp+1, bias of key 2jp)  [mod-64 rotation]
      const v2f bp = *(const v2f*)(prow + 62 - 2 * jp);
      const u64 kx = kq[jp * 4 + 0], ky = kq[jp * 4 + 1];
      const u64 kz = kq[jp * 4 + 2], kw = kq[jp * 4 + 3];
      v2f d = pkfma(qw2, kw, bp);   // w innermost with bias (same order as before)
      d = pkfma(qz2, kz, d);
      d = pkfma(qy2, ky, d);
      d = pkfma(qx2, kx, d);
      Z0 += __builtin_amdgcn_exp2f(d.x);
      Z1 += __builtin_amdgcn_exp2f(d.y);
    }
  }
  part[(chunk * 4 + bh) * Tt + t1] = Z0 + Z1;
}

// Kernel 3: reduce Z, diagonal softmax * v, out-proj + residual -> x2; then MLP conv1 (1x1 8->32) + gelu -> y1.
__global__ __launch_bounds__(64) void k_post(
    const float* __restrict__ part, const float* __restrict__ qo,
    const float* __restrict__ ko, const float* __restrict__ vo,
    const float* __restrict__ pos, const float* __restrict__ Wo,
    const float* __restrict__ x1, const float* __restrict__ W1,
    const float* __restrict__ b1, float* __restrict__ x2,
    float* __restrict__ y1) {
  const int gid = blockIdx.x * 64 + threadIdx.x;  // b*T + t
  const int b = gid >> 12, t = gid & 4095;
  float a[8];
#pragma unroll
  for (int h = 0; h < 2; h++) {
    const int bh = b * 2 + h;
    float Z = 0.0f;
#pragma unroll
    for (int c = 0; c < KCH; c++) Z += part[(c * 4 + bh) * Tt + t];
    const float4 qv = ((const float4*)qo)[bh * Tt + t];
    const float4 kv = ((const float4*)ko)[bh * Tt + t];
    const float4 vv = ((const float4*)vo)[bh * Tt + t];
    // diag logit: q already carries the 0.5*log2e scale; P[t,t] = pos[h,0,0]
    const float s = fmaf(qv.x, kv.x, fmaf(qv.y, kv.y,
                    fmaf(qv.z, kv.z, fmaf(qv.w, kv.w, QSCALE * pos[h * 4096]))));
    const float w = __builtin_amdgcn_exp2f(s) * __builtin_amdgcn_rcpf(Z);
    a[h * 4 + 0] = w * vv.x; a[h * 4 + 1] = w * vv.y;
    a[h * 4 + 2] = w * vv.z; a[h * 4 + 3] = w * vv.w;
  }
  const float4* px1 = (const float4*)(x1 + gid * 8);
  const float4 r0 = px1[0], r1 = px1[1];
  float res[8] = {r0.x, r0.y, r0.z, r0.w, r1.x, r1.y, r1.z, r1.w};
  float xv[8];
#pragma unroll
  for (int c = 0; c < 8; c++) {
    float s = res[c];
#pragma unroll
    for (int e = 0; e < 8; e++) s += a[e] * Wo[e * 8 + c];
    xv[c] = s;
  }
  float4* px2 = (float4*)(x2 + gid * 8);
  px2[0] = make_float4(xv[0], xv[1], xv[2], xv[3]);
  px2[1] = make_float4(xv[4], xv[5], xv[6], xv[7]);
  float y[8];
#pragma unroll
  for (int c = 0; c < 8; c++) y[c] = xv[c] * 0.5773502691896258f;  // 1/sqrt(3)
  float yv[32];
#pragma unroll
  for (int cc = 0; cc < 32; cc++) {
    float s = b1[cc];
#pragma unroll
    for (int c = 0; c < 8; c++) s += y[c] * W1[c * 32 + cc];
    yv[cc] = gelu_tanh(s);
  }
  float4* py = (float4*)(y1 + gid * 32);
#pragma unroll
  for (int qd = 0; qd < 8; qd++)
    py[qd] = make_float4(yv[qd * 4], yv[qd * 4 + 1], yv[qd * 4 + 2], yv[qd * 4 + 3]);
}

// Kernel 4: depthwise circ-conv 3x3 (32ch) + gelu, then 1x1 32->8 + b3 + residual(x2) -> out.
__global__ __launch_bounds__(64) void k_mlp23(
    const float* __restrict__ y1, const float* __restrict__ W2,
    const float* __restrict__ b2, const float* __restrict__ W3,
    const float* __restrict__ b3, const float* __restrict__ x2,
    float* __restrict__ out) {
  const int gid = blockIdx.x * 64 + threadIdx.x;
  const int b = gid >> 12, t = gid & 4095;
  const int i = t >> 6, j = t & 63;
  float acc[32];
#pragma unroll
  for (int cc = 0; cc < 32; cc++) acc[cc] = b2[cc];
#pragma unroll
  for (int di = 0; di < 3; di++) {
    const int ii = (i + di + 63) & 63;
#pragma unroll
    for (int dj = 0; dj < 3; dj++) {
      const int jj = (j + dj + 63) & 63;
      const float4* p = (const float4*)(y1 + ((b * 4096 + ii * 64 + jj) * 32));
      const float* w = W2 + (di * 3 + dj) * 32;
#pragma unroll
      for (int cq = 0; cq < 8; cq++) {
        const float4 u = p[cq];
        acc[cq * 4 + 0] += u.x * w[cq * 4 + 0];
        acc[cq * 4 + 1] += u.y * w[cq * 4 + 1];
        acc[cq * 4 + 2] += u.z * w[cq * 4 + 2];
        acc[cq * 4 + 3] += u.w * w[cq * 4 + 3];
      }
    }
  }
#pragma unroll
  for (int cc = 0; cc < 32; cc++) acc[cc] = gelu_tanh(acc[cc]);
  const float4* px2 = (const float4*)(x2 + gid * 8);
  const float4 r0 = px2[0], r1 = px2[1];
  float o[8] = {r0.x + b3[0], r0.y + b3[1], r0.z + b3[2], r0.w + b3[3],
                r1.x + b3[4], r1.y + b3[5], r1.z + b3[6], r1.w + b3[7]};
#pragma unroll
  for (int cc = 0; cc < 32; cc++) {
    const float v = acc[cc];
#pragma unroll
    for (int c = 0; c < 8; c++) o[c] += v * W3[cc * 8 + c];
  }
  float4* po = (float4*)(out + gid * 8);
  po[0] = make_float4(o[0], o[1], o[2], o[3]);
  po[1] = make_float4(o[4], o[5], o[6], o[7]);
}

extern "C" void kernel_launch(void* const* d_in, const int* in_sizes, int n_in,
                              void* d_out, int out_size, void* d_ws, size_t ws_size,
                              hipStream_t stream) {
  const float* x  = (const float*)d_in[0];
  const float* cW = (const float*)d_in[1];
  const float* cb = (const float*)d_in[2];
  const float* Wq = (const float*)d_in[3];
  const float* Wk = (const float*)d_in[4];
  const float* Wv = (const float*)d_in[5];
  const float* pos = (const float*)d_in[6];
  const float* Wo = (const float*)d_in[7];
  const float* W1 = (const float*)d_in[8];
  const float* b1 = (const float*)d_in[9];
  const float* W2 = (const float*)d_in[10];
  const float* b2 = (const float*)d_in[11];
  const float* W3 = (const float*)d_in[12];
  const float* b3 = (const float*)d_in[13];

  float* ws   = (float*)d_ws;
  float* x1   = ws;              // 65536
  float* qo   = ws + 65536;      // 65536
  float* ko   = ws + 131072;     // 65536
  float* vo   = ws + 196608;     // 65536
  float* part = ws + 262144;     // 262144
  float* x2   = ws + 524288;     // 65536
  float* y1   = ws + 589824;     // 262144
  float* kpk  = ws + 851968;     // 65536 (pair-interleaved K)
  float* out  = (float*)d_out;

  hipLaunchKernelGGL(k_pre,   dim3(128),  dim3(64), 0, stream, x, cW, cb, Wq, Wk, Wv, x1, qo, ko, vo, kpk);
  hipLaunchKernelGGL(k_attn,  dim3(4096), dim3(64), 0, stream, qo, kpk, pos, part);
  hipLaunchKernelGGL(k_post,  dim3(128),  dim3(64), 0, stream, part, qo, ko, vo, pos, Wo, x1, W1, b1, x2, y1);
  hipLaunchKernelGGL(k_mlp23, dim3(128),  dim3(64), 0, stream, y1, W2, b2, W3, b3, x2, out);
}

// Round 4
// 131.998 us; speedup vs baseline: 1.2073x; 1.2073x over previous
//
#include <hip/hip_runtime.h>
#include <math.h>

#define Tt 4096
#define KCH 16

// 0.5 * log2(e): folds the 1/sqrt(d)=0.5 softmax scale AND the base-e->base-2
// conversion into q (and the bias table), so the inner loop uses raw v_exp_f32.
#define QSCALE 0.72134752044448170f

__device__ __forceinline__ float gelu_tanh(float x) {
  // 0.7978845608 * 2 * log2(e) = 2.3022081159 ; e^{2u} computed as exp2.
  float x3 = x * x * x;
  float u2 = 2.3022081159f * (x + 0.044715f * x3);
  float e = __builtin_amdgcn_exp2f(u2);
  float th = 1.0f - 2.0f * __builtin_amdgcn_rcpf(e + 1.0f);
  return 0.5f * x * (1.0f + th);
}

// Kernel 1: x1 = circ_conv3x3(gelu(x)) + x ; then q,k,v projections from y=x1/sqrt(2).
// q is pre-scaled by 0.5*log2(e) (softmax scale + exp2 conversion).
__global__ __launch_bounds__(64) void k_pre(
    const float* __restrict__ x, const float* __restrict__ cW,
    const float* __restrict__ cb, const float* __restrict__ Wq,
    const float* __restrict__ Wk, const float* __restrict__ Wv,
    float* __restrict__ x1, float* __restrict__ qo,
    float* __restrict__ ko, float* __restrict__ vo) {
  const int bi = blockIdx.x;          // b*64 + i
  const int b = bi >> 6, i = bi & 63;
  const int j = threadIdx.x;          // 0..63
  float acc[8];
#pragma unroll
  for (int c = 0; c < 8; c++) acc[c] = cb[c];
#pragma unroll
  for (int di = 0; di < 3; di++) {
    const int ii = (i + di + 63) & 63;
#pragma unroll
    for (int dj = 0; dj < 3; dj++) {
      const int jj = (j + dj + 63) & 63;
      const float4* px = (const float4*)(x + ((b * 64 + ii) * 64 + jj) * 8);
      float4 a0 = px[0], a1 = px[1];
      float g[8];
      g[0] = gelu_tanh(a0.x); g[1] = gelu_tanh(a0.y);
      g[2] = gelu_tanh(a0.z); g[3] = gelu_tanh(a0.w);
      g[4] = gelu_tanh(a1.x); g[5] = gelu_tanh(a1.y);
      g[6] = gelu_tanh(a1.z); g[7] = gelu_tanh(a1.w);
      const float* w = cW + (di * 3 + dj) * 64;
#pragma unroll
      for (int ci = 0; ci < 8; ci++) {
        const float gv = g[ci];
#pragma unroll
        for (int c = 0; c < 8; c++) acc[c] += gv * w[ci * 8 + c];
      }
    }
  }
  const int t = i * 64 + j;
  const float4* pxc = (const float4*)(x + (b * Tt + t) * 8);
  float4 c0 = pxc[0], c1 = pxc[1];
  float xv[8];
  xv[0] = acc[0] + c0.x; xv[1] = acc[1] + c0.y;
  xv[2] = acc[2] + c0.z; xv[3] = acc[3] + c0.w;
  xv[4] = acc[4] + c1.x; xv[5] = acc[5] + c1.y;
  xv[6] = acc[6] + c1.z; xv[7] = acc[7] + c1.w;
  float4* px1 = (float4*)(x1 + (b * Tt + t) * 8);
  px1[0] = make_float4(xv[0], xv[1], xv[2], xv[3]);
  px1[1] = make_float4(xv[4], xv[5], xv[6], xv[7]);
  float y[8];
#pragma unroll
  for (int c = 0; c < 8; c++) y[c] = xv[c] * 0.7071067811865475f;
#pragma unroll
  for (int h = 0; h < 2; h++) {
    float qe[4], ke[4], ve[4];
#pragma unroll
    for (int d = 0; d < 4; d++) {
      const int e = h * 4 + d;
      float sq = 0.f, sk = 0.f, sv = 0.f;
#pragma unroll
      for (int c = 0; c < 8; c++) {
        sq += y[c] * Wq[c * 8 + e];
        sk += y[c] * Wk[c * 8 + e];
        sv += y[c] * Wv[c * 8 + e];
      }
      qe[d] = sq * QSCALE;  // fold softmax scale + log2(e) into q
      ke[d] = sk; ve[d] = sv;
    }
    const int idx = (b * 2 + h) * Tt + t;
    ((float4*)qo)[idx] = make_float4(qe[0], qe[1], qe[2], qe[3]);
    ((float4*)ko)[idx] = make_float4(ke[0], ke[1], ke[2], ke[3]);
    ((float4*)vo)[idx] = make_float4(ve[0], ve[1], ve[2], ve[3]);
  }
}

// Kernel 2: split-K softmax denominator. Z_t = sum_j exp2(q_t.k_j + c*P[t,j]).
// Bias table doubled (period 64) -> affine LDS index (loop-invariant vaddr +
// compile-time ds_read offsets). The K pointer carries an opaque zero VGPR
// offset so the wave-uniform K loads stay on the VMEM path (global_load,
// vmcnt) instead of being promoted to SMEM: SMEM shares lgkmcnt with the DS
// bias reads and returns out-of-order, forcing lgkmcnt(0) full drains per
// iteration. With vmcnt/lgkmcnt split, K loads and bias reads pipeline
// independently.
__global__ __launch_bounds__(64) void k_attn(
    const float* __restrict__ qo, const float* __restrict__ ko,
    const float* __restrict__ pos, float* __restrict__ part) {
  const int id = blockIdx.x;
  const int qblk = id & 63;
  const int bh = (id >> 6) & 3;
  const int chunk = id >> 8;
  const int h = bh & 1;
  const int lane = threadIdx.x;
  __shared__ float posr[4][128];
#pragma unroll
  for (int r = 0; r < 4; r++) {
    const int j1 = chunk * 4 + r;
    const int row = (qblk - j1) & 63;   // i1 = qblk (query row, wave-uniform)
    const float v = QSCALE * pos[(h * 64 + row) * 64 + lane];
    posr[r][lane] = v;
    posr[r][lane + 64] = v;             // period-64 duplicate
  }
  __syncthreads();
  const int t1 = qblk * 64 + lane;
  const float4 qv = ((const float4*)qo)[bh * Tt + t1];
  // Opaque zero in a VGPR: the compiler cannot fold it, so K addresses are
  // VGPR-based -> global_load (vmcnt), not s_load (lgkmcnt). All lanes load
  // the same address -> one broadcast L1 transaction.
  int zo;
  asm volatile("v_mov_b32 %0, 0" : "=v"(zo));
  const float4* kp = (const float4*)ko + bh * Tt + chunk * 256 + zo;
  float Z0 = 0.0f, Z1 = 0.0f;
#pragma unroll
  for (int r = 0; r < 4; r++) {
    const float* prow = &posr[r][lane + 1];  // + (63 - j2) -> (lane-j2) mod 64
    const float4* kr = kp + r * 64;
#pragma unroll 8
    for (int j2 = 0; j2 < 64; j2 += 2) {
      const float4 ka = kr[j2];            // global_load_dwordx4, broadcast
      const float4 kb = kr[j2 + 1];
      const float ba = prow[63 - j2];      // ds_read2_b32, immediate offsets
      const float bb = prow[62 - j2];
      const float sa = fmaf(qv.x, ka.x, fmaf(qv.y, ka.y,
                       fmaf(qv.z, ka.z, fmaf(qv.w, ka.w, ba))));
      const float sb = fmaf(qv.x, kb.x, fmaf(qv.y, kb.y,
                       fmaf(qv.z, kb.z, fmaf(qv.w, kb.w, bb))));
      Z0 += __builtin_amdgcn_exp2f(sa);
      Z1 += __builtin_amdgcn_exp2f(sb);
    }
  }
  part[(chunk * 4 + bh) * Tt + t1] = Z0 + Z1;
}

// Kernel 3: reduce Z, diagonal softmax * v, out-proj + residual -> x2; then MLP conv1 (1x1 8->32) + gelu -> y1.
__global__ __launch_bounds__(64) void k_post(
    const float* __restrict__ part, const float* __restrict__ qo,
    const float* __restrict__ ko, const float* __restrict__ vo,
    const float* __restrict__ pos, const float* __restrict__ Wo,
    const float* __restrict__ x1, const float* __restrict__ W1,
    const float* __restrict__ b1, float* __restrict__ x2,
    float* __restrict__ y1) {
  const int gid = blockIdx.x * 64 + threadIdx.x;  // b*T + t
  const int b = gid >> 12, t = gid & 4095;
  float a[8];
#pragma unroll
  for (int h = 0; h < 2; h++) {
    const int bh = b * 2 + h;
    float Z = 0.0f;
#pragma unroll
    for (int c = 0; c < KCH; c++) Z += part[(c * 4 + bh) * Tt + t];
    const float4 qv = ((const float4*)qo)[bh * Tt + t];
    const float4 kv = ((const float4*)ko)[bh * Tt + t];
    const float4 vv = ((const float4*)vo)[bh * Tt + t];
    // diag logit: q already carries the 0.5*log2e scale; P[t,t] = pos[h,0,0]
    const float s = fmaf(qv.x, kv.x, fmaf(qv.y, kv.y,
                    fmaf(qv.z, kv.z, fmaf(qv.w, kv.w, QSCALE * pos[h * 4096]))));
    const float w = __builtin_amdgcn_exp2f(s) * __builtin_amdgcn_rcpf(Z);
    a[h * 4 + 0] = w * vv.x; a[h * 4 + 1] = w * vv.y;
    a[h * 4 + 2] = w * vv.z; a[h * 4 + 3] = w * vv.w;
  }
  const float4* px1 = (const float4*)(x1 + gid * 8);
  const float4 r0 = px1[0], r1 = px1[1];
  float res[8] = {r0.x, r0.y, r0.z, r0.w, r1.x, r1.y, r1.z, r1.w};
  float xv[8];
#pragma unroll
  for (int c = 0; c < 8; c++) {
    float s = res[c];
#pragma unroll
    for (int e = 0; e < 8; e++) s += a[e] * Wo[e * 8 + c];
    xv[c] = s;
  }
  float4* px2 = (float4*)(x2 + gid * 8);
  px2[0] = make_float4(xv[0], xv[1], xv[2], xv[3]);
  px2[1] = make_float4(xv[4], xv[5], xv[6], xv[7]);
  float y[8];
#pragma unroll
  for (int c = 0; c < 8; c++) y[c] = xv[c] * 0.5773502691896258f;  // 1/sqrt(3)
  float yv[32];
#pragma unroll
  for (int cc = 0; cc < 32; cc++) {
    float s = b1[cc];
#pragma unroll
    for (int c = 0; c < 8; c++) s += y[c] * W1[c * 32 + cc];
    yv[cc] = gelu_tanh(s);
  }
  float4* py = (float4*)(y1 + gid * 32);
#pragma unroll
  for (int qd = 0; qd < 8; qd++)
    py[qd] = make_float4(yv[qd * 4], yv[qd * 4 + 1], yv[qd * 4 + 2], yv[qd * 4 + 3]);
}

// Kernel 4: depthwise circ-conv 3x3 (32ch) + gelu, then 1x1 32->8 + b3 + residual(x2) -> out.
__global__ __launch_bounds__(64) void k_mlp23(
    const float* __restrict__ y1, const float* __restrict__ W2,
    const float* __restrict__ b2, const float* __restrict__ W3,
    const float* __restrict__ b3, const float* __restrict__ x2,
    float* __restrict__ out) {
  const int gid = blockIdx.x * 64 + threadIdx.x;
  const int b = gid >> 12, t = gid & 4095;
  const int i = t >> 6, j = t & 63;
  float acc[32];
#pragma unroll
  for (int cc = 0; cc < 32; cc++) acc[cc] = b2[cc];
#pragma unroll
  for (int di = 0; di < 3; di++) {
    const int ii = (i + di + 63) & 63;
#pragma unroll
    for (int dj = 0; dj < 3; dj++) {
      const int jj = (j + dj + 63) & 63;
      const float4* p = (const float4*)(y1 + ((b * 4096 + ii * 64 + jj) * 32));
      const float* w = W2 + (di * 3 + dj) * 32;
#pragma unroll
      for (int cq = 0; cq < 8; cq++) {
        const float4 u = p[cq];
        acc[cq * 4 + 0] += u.x * w[cq * 4 + 0];
        acc[cq * 4 + 1] += u.y * w[cq * 4 + 1];
        acc[cq * 4 + 2] += u.z * w[cq * 4 + 2];
        acc[cq * 4 + 3] += u.w * w[cq * 4 + 3];
      }
    }
  }
#pragma unroll
  for (int cc = 0; cc < 32; cc++) acc[cc] = gelu_tanh(acc[cc]);
  const float4* px2 = (const float4*)(x2 + gid * 8);
  const float4 r0 = px2[0], r1 = px2[1];
  float o[8] = {r0.x + b3[0], r0.y + b3[1], r0.z + b3[2], r0.w + b3[3],
                r1.x + b3[4], r1.y + b3[5], r1.z + b3[6], r1.w + b3[7]};
#pragma unroll
  for (int cc = 0; cc < 32; cc++) {
    const float v = acc[cc];
#pragma unroll
    for (int c = 0; c < 8; c++) o[c] += v * W3[cc * 8 + c];
  }
  float4* po = (float4*)(out + gid * 8);
  po[0] = make_float4(o[0], o[1], o[2], o[3]);
  po[1] = make_float4(o[4], o[5], o[6], o[7]);
}

extern "C" void kernel_launch(void* const* d_in, const int* in_sizes, int n_in,
                              void* d_out, int out_size, void* d_ws, size_t ws_size,
                              hipStream_t stream) {
  const float* x  = (const float*)d_in[0];
  const float* cW = (const float*)d_in[1];
  const float* cb = (const float*)d_in[2];
  const float* Wq = (const float*)d_in[3];
  const float* Wk = (const float*)d_in[4];
  const float* Wv = (const float*)d_in[5];
  const float* pos = (const float*)d_in[6];
  const float* Wo = (const float*)d_in[7];
  const float* W1 = (const float*)d_in[8];
  const float* b1 = (const float*)d_in[9];
  const float* W2 = (const float*)d_in[10];
  const float* b2 = (const float*)d_in[11];
  const float* W3 = (const float*)d_in[12];
  const float* b3 = (const float*)d_in[13];

  float* ws   = (float*)d_ws;
  float* x1   = ws;              // 65536
  float* qo   = ws + 65536;      // 65536
  float* ko   = ws + 131072;     // 65536
  float* vo   = ws + 196608;     // 65536
  float* part = ws + 262144;     // 262144
  float* x2   = ws + 524288;     // 65536
  float* y1   = ws + 589824;     // 262144
  float* out  = (float*)d_out;

  hipLaunchKernelGGL(k_pre,   dim3(128),  dim3(64), 0, stream, x, cW, cb, Wq, Wk, Wv, x1, qo, ko, vo);
  hipLaunchKernelGGL(k_attn,  dim3(4096), dim3(64), 0, stream, qo, ko, pos, part);
  hipLaunchKernelGGL(k_post,  dim3(128),  dim3(64), 0, stream, part, qo, ko, vo, pos, Wo, x1, W1, b1, x2, y1);
  hipLaunchKernelGGL(k_mlp23, dim3(128),  dim3(64), 0, stream, y1, W2, b2, W3, b3, x2, out);
}

// Round 5
// 116.931 us; speedup vs baseline: 1.3628x; 1.1289x over previous
//
#include <hip/hip_runtime.h>
#include <math.h>

#define Tt 4096
#define KCH 16

// 0.5 * log2(e): folds the 1/sqrt(d)=0.5 softmax scale AND the base-e->base-2
// conversion into q (and the bias table), so the inner loop uses raw v_exp_f32.
#define QSCALE 0.72134752044448170f

__device__ __forceinline__ float gelu_tanh(float x) {
  // 0.7978845608 * 2 * log2(e) = 2.3022081159 ; e^{2u} computed as exp2.
  float x3 = x * x * x;
  float u2 = 2.3022081159f * (x + 0.044715f * x3);
  float e = __builtin_amdgcn_exp2f(u2);
  float th = 1.0f - 2.0f * __builtin_amdgcn_rcpf(e + 1.0f);
  return 0.5f * x * (1.0f + th);
}

// Kernel 1: x1 = circ_conv3x3(gelu(x)) + x ; then q,k,v projections from y=x1/sqrt(2).
// q is pre-scaled by 0.5*log2(e) (softmax scale + exp2 conversion).
__global__ __launch_bounds__(64) void k_pre(
    const float* __restrict__ x, const float* __restrict__ cW,
    const float* __restrict__ cb, const float* __restrict__ Wq,
    const float* __restrict__ Wk, const float* __restrict__ Wv,
    float* __restrict__ x1, float* __restrict__ qo,
    float* __restrict__ ko, float* __restrict__ vo) {
  const int bi = blockIdx.x;          // b*64 + i
  const int b = bi >> 6, i = bi & 63;
  const int j = threadIdx.x;          // 0..63
  float acc[8];
#pragma unroll
  for (int c = 0; c < 8; c++) acc[c] = cb[c];
#pragma unroll
  for (int di = 0; di < 3; di++) {
    const int ii = (i + di + 63) & 63;
#pragma unroll
    for (int dj = 0; dj < 3; dj++) {
      const int jj = (j + dj + 63) & 63;
      const float4* px = (const float4*)(x + ((b * 64 + ii) * 64 + jj) * 8);
      float4 a0 = px[0], a1 = px[1];
      float g[8];
      g[0] = gelu_tanh(a0.x); g[1] = gelu_tanh(a0.y);
      g[2] = gelu_tanh(a0.z); g[3] = gelu_tanh(a0.w);
      g[4] = gelu_tanh(a1.x); g[5] = gelu_tanh(a1.y);
      g[6] = gelu_tanh(a1.z); g[7] = gelu_tanh(a1.w);
      const float* w = cW + (di * 3 + dj) * 64;
#pragma unroll
      for (int ci = 0; ci < 8; ci++) {
        const float gv = g[ci];
#pragma unroll
        for (int c = 0; c < 8; c++) acc[c] += gv * w[ci * 8 + c];
      }
    }
  }
  const int t = i * 64 + j;
  const float4* pxc = (const float4*)(x + (b * Tt + t) * 8);
  float4 c0 = pxc[0], c1 = pxc[1];
  float xv[8];
  xv[0] = acc[0] + c0.x; xv[1] = acc[1] + c0.y;
  xv[2] = acc[2] + c0.z; xv[3] = acc[3] + c0.w;
  xv[4] = acc[4] + c1.x; xv[5] = acc[5] + c1.y;
  xv[6] = acc[6] + c1.z; xv[7] = acc[7] + c1.w;
  float4* px1 = (float4*)(x1 + (b * Tt + t) * 8);
  px1[0] = make_float4(xv[0], xv[1], xv[2], xv[3]);
  px1[1] = make_float4(xv[4], xv[5], xv[6], xv[7]);
  float y[8];
#pragma unroll
  for (int c = 0; c < 8; c++) y[c] = xv[c] * 0.7071067811865475f;
#pragma unroll
  for (int h = 0; h < 2; h++) {
    float qe[4], ke[4], ve[4];
#pragma unroll
    for (int d = 0; d < 4; d++) {
      const int e = h * 4 + d;
      float sq = 0.f, sk = 0.f, sv = 0.f;
#pragma unroll
      for (int c = 0; c < 8; c++) {
        sq += y[c] * Wq[c * 8 + e];
        sk += y[c] * Wk[c * 8 + e];
        sv += y[c] * Wv[c * 8 + e];
      }
      qe[d] = sq * QSCALE;  // fold softmax scale + log2(e) into q
      ke[d] = sk; ve[d] = sv;
    }
    const int idx = (b * 2 + h) * Tt + t;
    ((float4*)qo)[idx] = make_float4(qe[0], qe[1], qe[2], qe[3]);
    ((float4*)ko)[idx] = make_float4(ke[0], ke[1], ke[2], ke[3]);
    ((float4*)vo)[idx] = make_float4(ve[0], ve[1], ve[2], ve[3]);
  }
}

// Kernel 2: split-K softmax denominator. Z_t = sum_j exp2(q_t.k_j + c*P[t,j]).
// K is staged into LDS once per block and read with wave-uniform ds_read_b128
// (broadcast, conflict-free). This makes EVERY in-loop lgkm op a DS op: DS
// completes in-order, so the compiler can use counted lgkmcnt(N) waits and
// software-pipeline the reads. (R2's s_load K path mixed out-of-order SMEM
// with DS on the same counter -> full lgkmcnt(0) drains, ~44 cyc/pair; R4's
// VMEM-broadcast path was worse, ~200cyc latency on vmcnt.)
__global__ __launch_bounds__(64) void k_attn(
    const float* __restrict__ qo, const float* __restrict__ ko,
    const float* __restrict__ pos, float* __restrict__ part) {
  const int id = blockIdx.x;
  const int qblk = id & 63;
  const int bh = (id >> 6) & 3;
  const int chunk = id >> 8;
  const int h = bh & 1;
  const int lane = threadIdx.x;
  __shared__ float posr[4][128];
  __shared__ float4 ks[256];          // this block's 256-key slice (4 KB)
#pragma unroll
  for (int r = 0; r < 4; r++) {
    const int j1 = chunk * 4 + r;
    const int row = (qblk - j1) & 63;   // i1 = qblk (query row, wave-uniform)
    const float v = QSCALE * pos[(h * 64 + row) * 64 + lane];
    posr[r][lane] = v;
    posr[r][lane + 64] = v;             // period-64 duplicate
  }
  // stage K: contiguous 256 float4, coalesced
  const float4* kp = (const float4*)ko + bh * Tt + chunk * 256;
#pragma unroll
  for (int c = 0; c < 4; c++) ks[c * 64 + lane] = kp[c * 64 + lane];
  __syncthreads();
  const int t1 = qblk * 64 + lane;
  const float4 qv = ((const float4*)qo)[bh * Tt + t1];
  float Z0 = 0.0f, Z1 = 0.0f;
#pragma unroll
  for (int r = 0; r < 4; r++) {
    const float* prow = &posr[r][lane + 1];  // + (63 - j2) -> (lane-j2) mod 64
    const float4* kr = &ks[r * 64];
#pragma unroll 8
    for (int j2 = 0; j2 < 64; j2 += 2) {
      const float4 ka = kr[j2];            // ds_read_b128, wave-uniform broadcast
      const float4 kb = kr[j2 + 1];
      const float ba = prow[63 - j2];      // ds_read2_b32, immediate offsets
      const float bb = prow[62 - j2];
      const float sa = fmaf(qv.x, ka.x, fmaf(qv.y, ka.y,
                       fmaf(qv.z, ka.z, fmaf(qv.w, ka.w, ba))));
      const float sb = fmaf(qv.x, kb.x, fmaf(qv.y, kb.y,
                       fmaf(qv.z, kb.z, fmaf(qv.w, kb.w, bb))));
      Z0 += __builtin_amdgcn_exp2f(sa);
      Z1 += __builtin_amdgcn_exp2f(sb);
    }
  }
  part[(chunk * 4 + bh) * Tt + t1] = Z0 + Z1;
}

// Kernel 3: reduce Z, diagonal softmax * v, out-proj + residual -> x2; then MLP conv1 (1x1 8->32) + gelu -> y1.
__global__ __launch_bounds__(64) void k_post(
    const float* __restrict__ part, const float* __restrict__ qo,
    const float* __restrict__ ko, const float* __restrict__ vo,
    const float* __restrict__ pos, const float* __restrict__ Wo,
    const float* __restrict__ x1, const float* __restrict__ W1,
    const float* __restrict__ b1, float* __restrict__ x2,
    float* __restrict__ y1) {
  const int gid = blockIdx.x * 64 + threadIdx.x;  // b*T + t
  const int b = gid >> 12, t = gid & 4095;
  float a[8];
#pragma unroll
  for (int h = 0; h < 2; h++) {
    const int bh = b * 2 + h;
    float Z = 0.0f;
#pragma unroll
    for (int c = 0; c < KCH; c++) Z += part[(c * 4 + bh) * Tt + t];
    const float4 qv = ((const float4*)qo)[bh * Tt + t];
    const float4 kv = ((const float4*)ko)[bh * Tt + t];
    const float4 vv = ((const float4*)vo)[bh * Tt + t];
    // diag logit: q already carries the 0.5*log2e scale; P[t,t] = pos[h,0,0]
    const float s = fmaf(qv.x, kv.x, fmaf(qv.y, kv.y,
                    fmaf(qv.z, kv.z, fmaf(qv.w, kv.w, QSCALE * pos[h * 4096]))));
    const float w = __builtin_amdgcn_exp2f(s) * __builtin_amdgcn_rcpf(Z);
    a[h * 4 + 0] = w * vv.x; a[h * 4 + 1] = w * vv.y;
    a[h * 4 + 2] = w * vv.z; a[h * 4 + 3] = w * vv.w;
  }
  const float4* px1 = (const float4*)(x1 + gid * 8);
  const float4 r0 = px1[0], r1 = px1[1];
  float res[8] = {r0.x, r0.y, r0.z, r0.w, r1.x, r1.y, r1.z, r1.w};
  float xv[8];
#pragma unroll
  for (int c = 0; c < 8; c++) {
    float s = res[c];
#pragma unroll
    for (int e = 0; e < 8; e++) s += a[e] * Wo[e * 8 + c];
    xv[c] = s;
  }
  float4* px2 = (float4*)(x2 + gid * 8);
  px2[0] = make_float4(xv[0], xv[1], xv[2], xv[3]);
  px2[1] = make_float4(xv[4], xv[5], xv[6], xv[7]);
  float y[8];
#pragma unroll
  for (int c = 0; c < 8; c++) y[c] = xv[c] * 0.5773502691896258f;  // 1/sqrt(3)
  float yv[32];
#pragma unroll
  for (int cc = 0; cc < 32; cc++) {
    float s = b1[cc];
#pragma unroll
    for (int c = 0; c < 8; c++) s += y[c] * W1[c * 32 + cc];
    yv[cc] = gelu_tanh(s);
  }
  float4* py = (float4*)(y1 + gid * 32);
#pragma unroll
  for (int qd = 0; qd < 8; qd++)
    py[qd] = make_float4(yv[qd * 4], yv[qd * 4 + 1], yv[qd * 4 + 2], yv[qd * 4 + 3]);
}

// Kernel 4: depthwise circ-conv 3x3 (32ch) + gelu, then 1x1 32->8 + b3 + residual(x2) -> out.
__global__ __launch_bounds__(64) void k_mlp23(
    const float* __restrict__ y1, const float* __restrict__ W2,
    const float* __restrict__ b2, const float* __restrict__ W3,
    const float* __restrict__ b3, const float* __restrict__ x2,
    float* __restrict__ out) {
  const int gid = blockIdx.x * 64 + threadIdx.x;
  const int b = gid >> 12, t = gid & 4095;
  const int i = t >> 6, j = t & 63;
  float acc[32];
#pragma unroll
  for (int cc = 0; cc < 32; cc++) acc[cc] = b2[cc];
#pragma unroll
  for (int di = 0; di < 3; di++) {
    const int ii = (i + di + 63) & 63;
#pragma unroll
    for (int dj = 0; dj < 3; dj++) {
      const int jj = (j + dj + 63) & 63;
      const float4* p = (const float4*)(y1 + ((b * 4096 + ii * 64 + jj) * 32));
      const float* w = W2 + (di * 3 + dj) * 32;
#pragma unroll
      for (int cq = 0; cq < 8; cq++) {
        const float4 u = p[cq];
        acc[cq * 4 + 0] += u.x * w[cq * 4 + 0];
        acc[cq * 4 + 1] += u.y * w[cq * 4 + 1];
        acc[cq * 4 + 2] += u.z * w[cq * 4 + 2];
        acc[cq * 4 + 3] += u.w * w[cq * 4 + 3];
      }
    }
  }
#pragma unroll
  for (int cc = 0; cc < 32; cc++) acc[cc] = gelu_tanh(acc[cc]);
  const float4* px2 = (const float4*)(x2 + gid * 8);
  const float4 r0 = px2[0], r1 = px2[1];
  float o[8] = {r0.x + b3[0], r0.y + b3[1], r0.z + b3[2], r0.w + b3[3],
                r1.x + b3[4], r1.y + b3[5], r1.z + b3[6], r1.w + b3[7]};
#pragma unroll
  for (int cc = 0; cc < 32; cc++) {
    const float v = acc[cc];
#pragma unroll
    for (int c = 0; c < 8; c++) o[c] += v * W3[cc * 8 + c];
  }
  float4* po = (float4*)(out + gid * 8);
  po[0] = make_float4(o[0], o[1], o[2], o[3]);
  po[1] = make_float4(o[4], o[5], o[6], o[7]);
}

extern "C" void kernel_launch(void* const* d_in, const int* in_sizes, int n_in,
                              void* d_out, int out_size, void* d_ws, size_t ws_size,
                              hipStream_t stream) {
  const float* x  = (const float*)d_in[0];
  const float* cW = (const float*)d_in[1];
  const float* cb = (const float*)d_in[2];
  const float* Wq = (const float*)d_in[3];
  const float* Wk = (const float*)d_in[4];
  const float* Wv = (const float*)d_in[5];
  const float* pos = (const float*)d_in[6];
  const float* Wo = (const float*)d_in[7];
  const float* W1 = (const float*)d_in[8];
  const float* b1 = (const float*)d_in[9];
  const float* W2 = (const float*)d_in[10];
  const float* b2 = (const float*)d_in[11];
  const float* W3 = (const float*)d_in[12];
  const float* b3 = (const float*)d_in[13];

  float* ws   = (float*)d_ws;
  float* x1   = ws;              // 65536
  float* qo   = ws + 65536;      // 65536
  float* ko   = ws + 131072;     // 65536
  float* vo   = ws + 196608;     // 65536
  float* part = ws + 262144;     // 262144
  float* x2   = ws + 524288;     // 65536
  float* y1   = ws + 589824;     // 262144
  float* out  = (float*)d_out;

  hipLaunchKernelGGL(k_pre,   dim3(128),  dim3(64), 0, stream, x, cW, cb, Wq, Wk, Wv, x1, qo, ko, vo);
  hipLaunchKernelGGL(k_attn,  dim3(4096), dim3(64), 0, stream, qo, ko, pos, part);
  hipLaunchKernelGGL(k_post,  dim3(128),  dim3(64), 0, stream, part, qo, ko, vo, pos, Wo, x1, W1, b1, x2, y1);
  hipLaunchKernelGGL(k_mlp23, dim3(128),  dim3(64), 0, stream, y1, W2, b2, W3, b3, x2, out);
}

// Round 6
// 115.515 us; speedup vs baseline: 1.3795x; 1.0123x over previous
//
#include <hip/hip_runtime.h>
#include <math.h>

#define Tt 4096
#define KCH 32

// 0.5 * log2(e): folds the 1/sqrt(d)=0.5 softmax scale AND the base-e->base-2
// conversion into q (and the bias table), so the inner loop uses raw v_exp_f32.
#define QSCALE 0.72134752044448170f

__device__ __forceinline__ float gelu_tanh(float x) {
  // 0.7978845608 * 2 * log2(e) = 2.3022081159 ; e^{2u} computed as exp2.
  float x3 = x * x * x;
  float u2 = 2.3022081159f * (x + 0.044715f * x3);
  float e = __builtin_amdgcn_exp2f(u2);
  float th = 1.0f - 2.0f * __builtin_amdgcn_rcpf(e + 1.0f);
  return 0.5f * x * (1.0f + th);
}

// Kernel 1: x1 = circ_conv3x3(gelu(x)) + x ; then q,k,v projections from y=x1/sqrt(2).
// q is pre-scaled by 0.5*log2(e) (softmax scale + exp2 conversion).
__global__ __launch_bounds__(64) void k_pre(
    const float* __restrict__ x, const float* __restrict__ cW,
    const float* __restrict__ cb, const float* __restrict__ Wq,
    const float* __restrict__ Wk, const float* __restrict__ Wv,
    float* __restrict__ x1, float* __restrict__ qo,
    float* __restrict__ ko, float* __restrict__ vo) {
  const int bi = blockIdx.x;          // b*64 + i
  const int b = bi >> 6, i = bi & 63;
  const int j = threadIdx.x;          // 0..63
  float acc[8];
#pragma unroll
  for (int c = 0; c < 8; c++) acc[c] = cb[c];
#pragma unroll
  for (int di = 0; di < 3; di++) {
    const int ii = (i + di + 63) & 63;
#pragma unroll
    for (int dj = 0; dj < 3; dj++) {
      const int jj = (j + dj + 63) & 63;
      const float4* px = (const float4*)(x + ((b * 64 + ii) * 64 + jj) * 8);
      float4 a0 = px[0], a1 = px[1];
      float g[8];
      g[0] = gelu_tanh(a0.x); g[1] = gelu_tanh(a0.y);
      g[2] = gelu_tanh(a0.z); g[3] = gelu_tanh(a0.w);
      g[4] = gelu_tanh(a1.x); g[5] = gelu_tanh(a1.y);
      g[6] = gelu_tanh(a1.z); g[7] = gelu_tanh(a1.w);
      const float* w = cW + (di * 3 + dj) * 64;
#pragma unroll
      for (int ci = 0; ci < 8; ci++) {
        const float gv = g[ci];
#pragma unroll
        for (int c = 0; c < 8; c++) acc[c] += gv * w[ci * 8 + c];
      }
    }
  }
  const int t = i * 64 + j;
  const float4* pxc = (const float4*)(x + (b * Tt + t) * 8);
  float4 c0 = pxc[0], c1 = pxc[1];
  float xv[8];
  xv[0] = acc[0] + c0.x; xv[1] = acc[1] + c0.y;
  xv[2] = acc[2] + c0.z; xv[3] = acc[3] + c0.w;
  xv[4] = acc[4] + c1.x; xv[5] = acc[5] + c1.y;
  xv[6] = acc[6] + c1.z; xv[7] = acc[7] + c1.w;
  float4* px1 = (float4*)(x1 + (b * Tt + t) * 8);
  px1[0] = make_float4(xv[0], xv[1], xv[2], xv[3]);
  px1[1] = make_float4(xv[4], xv[5], xv[6], xv[7]);
  float y[8];
#pragma unroll
  for (int c = 0; c < 8; c++) y[c] = xv[c] * 0.7071067811865475f;
#pragma unroll
  for (int h = 0; h < 2; h++) {
    float qe[4], ke[4], ve[4];
#pragma unroll
    for (int d = 0; d < 4; d++) {
      const int e = h * 4 + d;
      float sq = 0.f, sk = 0.f, sv = 0.f;
#pragma unroll
      for (int c = 0; c < 8; c++) {
        sq += y[c] * Wq[c * 8 + e];
        sk += y[c] * Wk[c * 8 + e];
        sv += y[c] * Wv[c * 8 + e];
      }
      qe[d] = sq * QSCALE;  // fold softmax scale + log2(e) into q
      ke[d] = sk; ve[d] = sv;
    }
    const int idx = (b * 2 + h) * Tt + t;
    ((float4*)qo)[idx] = make_float4(qe[0], qe[1], qe[2], qe[3]);
    ((float4*)ko)[idx] = make_float4(ke[0], ke[1], ke[2], ke[3]);
    ((float4*)vo)[idx] = make_float4(ve[0], ve[1], ve[2], ve[3]);
  }
}

// Kernel 2: split-K softmax denominator. Z_t = sum_j exp2(q_t.k_j + c*P[t,j]).
// 2-wave blocks (two adjacent qblks) share one staged 128-key LDS slice:
// 4096 blocks x 2 waves -> 32 waves/CU under the 16-WG/CU slot cap (vs 16
// waves/CU for 1-wave blocks in R2-R5, which left DS latency uncovered:
// SMEM-K / VMEM-K / LDS-K all plateaued at 18-33 us). Inner loop arithmetic
// and staging pattern are identical to the verified R5 kernel.
__global__ __launch_bounds__(128) void k_attn(
    const float* __restrict__ qo, const float* __restrict__ ko,
    const float* __restrict__ pos, float* __restrict__ part) {
  const int id = blockIdx.x;          // ((chunk*4 + bh)*32 + qpair)
  const int qpair = id & 31;
  const int bh = (id >> 5) & 3;
  const int chunk = id >> 7;          // 0..31, 128 keys each
  const int h = bh & 1;
  const int wave = threadIdx.x >> 6;
  const int lane = threadIdx.x & 63;
  const int qblk = qpair * 2 + wave;
  __shared__ float posr[2][2][128];   // [wave][r][doubled cols]
  __shared__ float4 ks[128];          // this block's 128-key slice (2 KB)
#pragma unroll
  for (int r = 0; r < 2; r++) {
    const int j1 = chunk * 2 + r;
    const int row = (qblk - j1) & 63;   // i1 = qblk (query row, wave-uniform)
    const float v = QSCALE * pos[(h * 64 + row) * 64 + lane];
    posr[wave][r][lane] = v;
    posr[wave][r][lane + 64] = v;       // period-64 duplicate
  }
  // stage K: contiguous 128 float4, coalesced across the whole block
  const float4* kp = (const float4*)ko + bh * Tt + chunk * 128;
  ks[threadIdx.x] = kp[threadIdx.x];
  __syncthreads();
  const int t1 = qblk * 64 + lane;
  const float4 qv = ((const float4*)qo)[bh * Tt + t1];
  float Z0 = 0.0f, Z1 = 0.0f;
#pragma unroll
  for (int r = 0; r < 2; r++) {
    const float* prow = &posr[wave][r][lane + 1];  // +(63-j2) -> (lane-j2) mod 64
    const float4* kr = &ks[r * 64];
#pragma unroll 8
    for (int j2 = 0; j2 < 64; j2 += 2) {
      const float4 ka = kr[j2];            // ds_read_b128, wave-uniform broadcast
      const float4 kb = kr[j2 + 1];
      const float ba = prow[63 - j2];      // ds_read2_b32, immediate offsets
      const float bb = prow[62 - j2];
      const float sa = fmaf(qv.x, ka.x, fmaf(qv.y, ka.y,
                       fmaf(qv.z, ka.z, fmaf(qv.w, ka.w, ba))));
      const float sb = fmaf(qv.x, kb.x, fmaf(qv.y, kb.y,
                       fmaf(qv.z, kb.z, fmaf(qv.w, kb.w, bb))));
      Z0 += __builtin_amdgcn_exp2f(sa);
      Z1 += __builtin_amdgcn_exp2f(sb);
    }
  }
  part[(chunk * 4 + bh) * Tt + t1] = Z0 + Z1;
}

// Kernel 3: reduce Z, diagonal softmax * v, out-proj + residual -> x2; then MLP conv1 (1x1 8->32) + gelu -> y1.
__global__ __launch_bounds__(64) void k_post(
    const float* __restrict__ part, const float* __restrict__ qo,
    const float* __restrict__ ko, const float* __restrict__ vo,
    const float* __restrict__ pos, const float* __restrict__ Wo,
    const float* __restrict__ x1, const float* __restrict__ W1,
    const float* __restrict__ b1, float* __restrict__ x2,
    float* __restrict__ y1) {
  const int gid = blockIdx.x * 64 + threadIdx.x;  // b*T + t
  const int b = gid >> 12, t = gid & 4095;
  float a[8];
#pragma unroll
  for (int h = 0; h < 2; h++) {
    const int bh = b * 2 + h;
    float Z = 0.0f;
#pragma unroll
    for (int c = 0; c < KCH; c++) Z += part[(c * 4 + bh) * Tt + t];
    const float4 qv = ((const float4*)qo)[bh * Tt + t];
    const float4 kv = ((const float4*)ko)[bh * Tt + t];
    const float4 vv = ((const float4*)vo)[bh * Tt + t];
    // diag logit: q already carries the 0.5*log2e scale; P[t,t] = pos[h,0,0]
    const float s = fmaf(qv.x, kv.x, fmaf(qv.y, kv.y,
                    fmaf(qv.z, kv.z, fmaf(qv.w, kv.w, QSCALE * pos[h * 4096]))));
    const float w = __builtin_amdgcn_exp2f(s) * __builtin_amdgcn_rcpf(Z);
    a[h * 4 + 0] = w * vv.x; a[h * 4 + 1] = w * vv.y;
    a[h * 4 + 2] = w * vv.z; a[h * 4 + 3] = w * vv.w;
  }
  const float4* px1 = (const float4*)(x1 + gid * 8);
  const float4 r0 = px1[0], r1 = px1[1];
  float res[8] = {r0.x, r0.y, r0.z, r0.w, r1.x, r1.y, r1.z, r1.w};
  float xv[8];
#pragma unroll
  for (int c = 0; c < 8; c++) {
    float s = res[c];
#pragma unroll
    for (int e = 0; e < 8; e++) s += a[e] * Wo[e * 8 + c];
    xv[c] = s;
  }
  float4* px2 = (float4*)(x2 + gid * 8);
  px2[0] = make_float4(xv[0], xv[1], xv[2], xv[3]);
  px2[1] = make_float4(xv[4], xv[5], xv[6], xv[7]);
  float y[8];
#pragma unroll
  for (int c = 0; c < 8; c++) y[c] = xv[c] * 0.5773502691896258f;  // 1/sqrt(3)
  float yv[32];
#pragma unroll
  for (int cc = 0; cc < 32; cc++) {
    float s = b1[cc];
#pragma unroll
    for (int c = 0; c < 8; c++) s += y[c] * W1[c * 32 + cc];
    yv[cc] = gelu_tanh(s);
  }
  float4* py = (float4*)(y1 + gid * 32);
#pragma unroll
  for (int qd = 0; qd < 8; qd++)
    py[qd] = make_float4(yv[qd * 4], yv[qd * 4 + 1], yv[qd * 4 + 2], yv[qd * 4 + 3]);
}

// Kernel 4: depthwise circ-conv 3x3 (32ch) + gelu, then 1x1 32->8 + b3 + residual(x2) -> out.
__global__ __launch_bounds__(64) void k_mlp23(
    const float* __restrict__ y1, const float* __restrict__ W2,
    const float* __restrict__ b2, const float* __restrict__ W3,
    const float* __restrict__ b3, const float* __restrict__ x2,
    float* __restrict__ out) {
  const int gid = blockIdx.x * 64 + threadIdx.x;
  const int b = gid >> 12, t = gid & 4095;
  const int i = t >> 6, j = t & 63;
  float acc[32];
#pragma unroll
  for (int cc = 0; cc < 32; cc++) acc[cc] = b2[cc];
#pragma unroll
  for (int di = 0; di < 3; di++) {
    const int ii = (i + di + 63) & 63;
#pragma unroll
    for (int dj = 0; dj < 3; dj++) {
      const int jj = (j + dj + 63) & 63;
      const float4* p = (const float4*)(y1 + ((b * 4096 + ii * 64 + jj) * 32));
      const float* w = W2 + (di * 3 + dj) * 32;
#pragma unroll
      for (int cq = 0; cq < 8; cq++) {
        const float4 u = p[cq];
        acc[cq * 4 + 0] += u.x * w[cq * 4 + 0];
        acc[cq * 4 + 1] += u.y * w[cq * 4 + 1];
        acc[cq * 4 + 2] += u.z * w[cq * 4 + 2];
        acc[cq * 4 + 3] += u.w * w[cq * 4 + 3];
      }
    }
  }
#pragma unroll
  for (int cc = 0; cc < 32; cc++) acc[cc] = gelu_tanh(acc[cc]);
  const float4* px2 = (const float4*)(x2 + gid * 8);
  const float4 r0 = px2[0], r1 = px2[1];
  float o[8] = {r0.x + b3[0], r0.y + b3[1], r0.z + b3[2], r0.w + b3[3],
                r1.x + b3[4], r1.y + b3[5], r1.z + b3[6], r1.w + b3[7]};
#pragma unroll
  for (int cc = 0; cc < 32; cc++) {
    const float v = acc[cc];
#pragma unroll
    for (int c = 0; c < 8; c++) o[c] += v * W3[cc * 8 + c];
  }
  float4* po = (float4*)(out + gid * 8);
  po[0] = make_float4(o[0], o[1], o[2], o[3]);
  po[1] = make_float4(o[4], o[5], o[6], o[7]);
}

extern "C" void kernel_launch(void* const* d_in, const int* in_sizes, int n_in,
                              void* d_out, int out_size, void* d_ws, size_t ws_size,
                              hipStream_t stream) {
  const float* x  = (const float*)d_in[0];
  const float* cW = (const float*)d_in[1];
  const float* cb = (const float*)d_in[2];
  const float* Wq = (const float*)d_in[3];
  const float* Wk = (const float*)d_in[4];
  const float* Wv = (const float*)d_in[5];
  const float* pos = (const float*)d_in[6];
  const float* Wo = (const float*)d_in[7];
  const float* W1 = (const float*)d_in[8];
  const float* b1 = (const float*)d_in[9];
  const float* W2 = (const float*)d_in[10];
  const float* b2 = (const float*)d_in[11];
  const float* W3 = (const float*)d_in[12];
  const float* b3 = (const float*)d_in[13];

  float* ws   = (float*)d_ws;
  float* x1   = ws;              // 65536
  float* qo   = ws + 65536;      // 65536
  float* ko   = ws + 131072;     // 65536
  float* vo   = ws + 196608;     // 65536
  float* part = ws + 262144;     // 524288 (KCH=32 partials)
  float* x2   = ws + 786432;     // 65536
  float* y1   = ws + 851968;     // 262144
  float* out  = (float*)d_out;

  hipLaunchKernelGGL(k_pre,   dim3(128),  dim3(64),  0, stream, x, cW, cb, Wq, Wk, Wv, x1, qo, ko, vo);
  hipLaunchKernelGGL(k_attn,  dim3(4096), dim3(128), 0, stream, qo, ko, pos, part);
  hipLaunchKernelGGL(k_post,  dim3(128),  dim3(64),  0, stream, part, qo, ko, vo, pos, Wo, x1, W1, b1, x2, y1);
  hipLaunchKernelGGL(k_mlp23, dim3(128),  dim3(64),  0, stream, y1, W2, b2, W3, b3, x2, out);
}